// Round 14
// baseline (798.176 us; speedup 1.0000x reference)
//
#include <hip/hip_runtime.h>

typedef __attribute__((ext_vector_type(8))) __bf16 bf16x8;
typedef __attribute__((ext_vector_type(4))) __bf16 bf16x4;
typedef __attribute__((ext_vector_type(2))) __bf16 bf16x2;
typedef __attribute__((ext_vector_type(4))) float f32x4;

__device__ inline bf16x8 pack8(f32x4 u0, f32x4 u1) {
    bf16x8 r;
    r[0] = (__bf16)u0[0]; r[1] = (__bf16)u0[1]; r[2] = (__bf16)u0[2]; r[3] = (__bf16)u0[3];
    r[4] = (__bf16)u1[0]; r[5] = (__bf16)u1[1]; r[6] = (__bf16)u1[2]; r[7] = (__bf16)u1[3];
    return r;
}

// ---- pack all 4 weight blocks into MFMA B-fragment order (one launch) ----
__global__ void pack_all(const float* __restrict__ Wv, const float* __restrict__ Wf,
                         __bf16* __restrict__ Wtab_v, __bf16* __restrict__ Wedge_v,
                         __bf16* __restrict__ Wtab_f, __bf16* __restrict__ Wedge_f) {
    int which = blockIdx.x >> 7;                       // 0..3
    int i = ((blockIdx.x & 127) << 8) + threadIdx.x;   // 0..32767
    const float* W = (which < 2) ? Wv : Wf;
    __bf16* out = (which == 0) ? Wtab_v : (which == 1) ? Wedge_v
                 : (which == 2) ? Wtab_f : Wedge_f;
    int baseA = (which & 1) ? 128 : 0;
    float sA  = (which & 1) ? -1.f : 1.f;
    int baseB = (which & 1) ? 256 : 128;
    int k = i >> 7, d = i & 127;
    float v = (k < 128) ? sA * W[(long)(baseA + k) * 128 + d]
                        : W[(long)(baseB + (k - 128)) * 128 + d];
    int t = k >> 5, n = d >> 4;
    int lane = (d & 15) | (((k >> 3) & 3) << 4);
    int j = k & 7;
    out[((long)(t * 8 + n) * 64 + lane) * 8 + j] = (__bf16)v;
}

// ---- eattr [E][128] f32 -> efrag fragment order (bf16), fully coalesced ----
__global__ __launch_bounds__(256) void conv_eattr(
    const float* __restrict__ e, __bf16* __restrict__ efrag, int E, int nunits) {
    int gw = (int)(((long)blockIdx.x * blockDim.x + threadIdx.x) >> 6);
    if (gw >= nunits) return;
    int lane = threadIdx.x & 63;
    long row = (long)(gw >> 2) * 16 + (lane & 15);
    if (row >= E) row = E - 1;
    int k0 = (gw & 3) * 32 + (lane >> 4) * 8;
    const float* p = e + row * 128 + k0;
    f32x4 u0 = *(const f32x4*)p;
    f32x4 u1 = *(const f32x4*)(p + 4);
    *(bf16x8*)(efrag + (long)gw * 512 + lane * 8) = pack8(u0, u1);
}

// ================= CSR build (counts -> scan -> fill) =================

__global__ void hist_kernel(const int* __restrict__ v_to_f, const int* __restrict__ f_to_v,
                            int* __restrict__ counts, int V, int E) {
    int stride = gridDim.x * blockDim.x;
    for (int e = blockIdx.x * blockDim.x + threadIdx.x; e < E; e += stride) {
        atomicAdd(&counts[v_to_f[e]], 1);
        atomicAdd(&counts[V + f_to_v[e]], 1);
    }
}

#define SCAN_BLOCK 256
#define SCAN_ELEMS 4   // 1024 elements per block

__global__ void scan_pass1(const int* __restrict__ counts, int* __restrict__ partials, int N) {
    int t = threadIdx.x;
    int base = blockIdx.x * (SCAN_BLOCK * SCAN_ELEMS) + t * SCAN_ELEMS;
    int s = 0;
#pragma unroll
    for (int j = 0; j < SCAN_ELEMS; ++j) {
        int i = base + j;
        if (i < N) s += counts[i];
    }
#pragma unroll
    for (int off = 1; off < 64; off <<= 1) s += __shfl_xor(s, off);
    __shared__ int lds[4];
    if ((t & 63) == 0) lds[t >> 6] = s;
    __syncthreads();
    if (t == 0) partials[blockIdx.x] = lds[0] + lds[1] + lds[2] + lds[3];
}

__global__ void scan_pass3(const int* __restrict__ counts, const int* __restrict__ partials,
                           int* __restrict__ offsets, int* __restrict__ cursors,
                           int N, int total) {
    int t = threadIdx.x;
    int pre = 0;
    for (int i = 0; i < (int)blockIdx.x; ++i) pre += partials[i];
    int base = blockIdx.x * (SCAN_BLOCK * SCAN_ELEMS) + t * SCAN_ELEMS;
    int c[SCAN_ELEMS];
    int s = 0;
#pragma unroll
    for (int j = 0; j < SCAN_ELEMS; ++j) {
        int i = base + j;
        c[j] = (i < N) ? counts[i] : 0;
        s += c[j];
    }
    int lane = t & 63, w = t >> 6;
    int x = s;
#pragma unroll
    for (int off = 1; off < 64; off <<= 1) { int y = __shfl_up(x, off); if (lane >= off) x += y; }
    __shared__ int lds[4];
    if (lane == 63) lds[w] = x;
    __syncthreads();
    int add = 0;
    for (int i = 0; i < w; ++i) add += lds[i];
    int run = x + add - s + pre;
#pragma unroll
    for (int j = 0; j < SCAN_ELEMS; ++j) {
        int i = base + j;
        if (i < N) { offsets[i] = run; cursors[i] = run; }
        run += c[j];
    }
    if (blockIdx.x == 0 && t == 0) offsets[N] = total;
}

__global__ void fill_kernel(const int* __restrict__ v_to_f, const int* __restrict__ f_to_v,
                            int* __restrict__ cursors, int* __restrict__ bucket, int V, int E) {
    int stride = gridDim.x * blockDim.x;
    for (int e = blockIdx.x * blockDim.x + threadIdx.x; e < E; e += stride) {
        int p = atomicAdd(&cursors[v_to_f[e]], 1);
        bucket[p] = e;
        int q = atomicAdd(&cursors[V + f_to_v[e]], 1);
        bucket[q] = e;
    }
}

// ================= gather-sum (segment sum, no atomics, unroll-4) =================

__global__ __launch_bounds__(256) void gsum_f32(
    const float* __restrict__ src, const int* __restrict__ bucket,
    const int* __restrict__ offsets, int toff,
    float* __restrict__ sumout, __bf16* __restrict__ prevbf, int T) {
    int gw = (int)((blockIdx.x * (long)blockDim.x + threadIdx.x) >> 6);
    if (gw >= T) return;
    int lane = threadIdx.x & 63;
    int start = offsets[toff + gw], end = offsets[toff + gw + 1];
    float ax = 0.f, ay = 0.f, bx = 0.f, by = 0.f;
    float cx = 0.f, cy = 0.f, dx = 0.f, dy = 0.f;
    int i = start;
    for (; i + 3 < end; i += 4) {
        int e0 = bucket[i], e1 = bucket[i + 1], e2 = bucket[i + 2], e3 = bucket[i + 3];
        float2 v0 = *(const float2*)(src + (long)e0 * 128 + lane * 2);
        float2 v1 = *(const float2*)(src + (long)e1 * 128 + lane * 2);
        float2 v2 = *(const float2*)(src + (long)e2 * 128 + lane * 2);
        float2 v3 = *(const float2*)(src + (long)e3 * 128 + lane * 2);
        bf16x2 b0, b1, b2, b3;
        b0[0] = (__bf16)v0.x; b0[1] = (__bf16)v0.y;
        b1[0] = (__bf16)v1.x; b1[1] = (__bf16)v1.y;
        b2[0] = (__bf16)v2.x; b2[1] = (__bf16)v2.y;
        b3[0] = (__bf16)v3.x; b3[1] = (__bf16)v3.y;
        *(bf16x2*)(prevbf + (long)e0 * 128 + lane * 2) = b0;
        *(bf16x2*)(prevbf + (long)e1 * 128 + lane * 2) = b1;
        *(bf16x2*)(prevbf + (long)e2 * 128 + lane * 2) = b2;
        *(bf16x2*)(prevbf + (long)e3 * 128 + lane * 2) = b3;
        ax += v0.x; ay += v0.y; bx += v1.x; by += v1.y;
        cx += v2.x; cy += v2.y; dx += v3.x; dy += v3.y;
    }
    for (; i < end; ++i) {
        int e0 = bucket[i];
        float2 v0 = *(const float2*)(src + (long)e0 * 128 + lane * 2);
        bf16x2 b0;
        b0[0] = (__bf16)v0.x; b0[1] = (__bf16)v0.y;
        *(bf16x2*)(prevbf + (long)e0 * 128 + lane * 2) = b0;
        ax += v0.x; ay += v0.y;
    }
    ax += bx + cx + dx; ay += by + cy + dy;
    long o = (long)gw * 128 + lane * 2;
    *(float2*)(sumout + o) = make_float2(ax, ay);
}

__global__ __launch_bounds__(256) void gsum_bf16(
    const __bf16* __restrict__ src, const int* __restrict__ bucket,
    const int* __restrict__ offsets, int toff,
    float* __restrict__ sumout, int T) {
    int gw = (int)((blockIdx.x * (long)blockDim.x + threadIdx.x) >> 6);
    if (gw >= T) return;
    int lane = threadIdx.x & 63;
    int start = offsets[toff + gw], end = offsets[toff + gw + 1];
    float ax = 0.f, ay = 0.f, bx = 0.f, by = 0.f;
    float cx = 0.f, cy = 0.f, dx = 0.f, dy = 0.f;
    int i = start;
    for (; i + 3 < end; i += 4) {
        int e0 = bucket[i], e1 = bucket[i + 1], e2 = bucket[i + 2], e3 = bucket[i + 3];
        bf16x2 v0 = *(const bf16x2*)(src + (long)e0 * 128 + lane * 2);
        bf16x2 v1 = *(const bf16x2*)(src + (long)e1 * 128 + lane * 2);
        bf16x2 v2 = *(const bf16x2*)(src + (long)e2 * 128 + lane * 2);
        bf16x2 v3 = *(const bf16x2*)(src + (long)e3 * 128 + lane * 2);
        ax += (float)v0[0]; ay += (float)v0[1]; bx += (float)v1[0]; by += (float)v1[1];
        cx += (float)v2[0]; cy += (float)v2[1]; dx += (float)v3[0]; dy += (float)v3[1];
    }
    for (; i < end; ++i) {
        int e0 = bucket[i];
        bf16x2 v0 = *(const bf16x2*)(src + (long)e0 * 128 + lane * 2);
        ax += (float)v0[0]; ay += (float)v0[1];
    }
    ax += bx + cx + dx; ay += by + cy + dy;
    long o = (long)gw * 128 + lane * 2;
    *(float2*)(sumout + o) = make_float2(ax, ay);
}

// ====== table GEMM: G[r] = src0[r]@WA + src1[r]@WB + bias; addout = src0+src1 ======
__global__ __launch_bounds__(256, 4) void table_gemm(
    const float* __restrict__ src0, const float* __restrict__ src1,
    const __bf16* __restrict__ WT, const float* __restrict__ bias,
    __bf16* __restrict__ out, float* __restrict__ addout, int T) {
    const int wave = threadIdx.x >> 6;
    const int lane = threadIdx.x & 63;
    const int row = lane & 15;
    const int kch = lane >> 4;
    const long wbase = ((long)blockIdx.x * 4 + wave) * 32;

    const float* p0[2]; const float* p1[2];
#pragma unroll
    for (int rb = 0; rb < 2; ++rb) {
        long r = wbase + rb * 16 + row;
        long rl = (r < T) ? r : (T - 1);
        p0[rb] = src0 + rl * 128 + kch * 8;
        p1[rb] = src1 + rl * 128 + kch * 8;
    }

    f32x4 acc[8][2];
#pragma unroll
    for (int n = 0; n < 8; ++n) {
        acc[n][0] = (f32x4){0.f, 0.f, 0.f, 0.f};
        acc[n][1] = (f32x4){0.f, 0.f, 0.f, 0.f};
    }

#pragma unroll
    for (int t = 0; t < 8; ++t) {
        bf16x8 a[2];
#pragma unroll
        for (int rb = 0; rb < 2; ++rb) {
            const float* p = (t < 4) ? (p0[rb] + t * 32) : (p1[rb] + (t - 4) * 32);
            f32x4 u0 = *(const f32x4*)p;
            f32x4 u1 = *(const f32x4*)(p + 4);
            a[rb] = pack8(u0, u1);
        }
        const __bf16* bbase = WT + (long)t * 8 * 512 + lane * 8;
#pragma unroll
        for (int n = 0; n < 8; ++n) {
            bf16x8 b = *(const bf16x8*)(bbase + n * 512);
            acc[n][0] = __builtin_amdgcn_mfma_f32_16x16x32_bf16(a[0], b, acc[n][0], 0, 0, 0);
            acc[n][1] = __builtin_amdgcn_mfma_f32_16x16x32_bf16(a[1], b, acc[n][1], 0, 0, 0);
        }
    }

    const int colbase = lane & 15;
    const int orow = (lane >> 4) * 4;
#pragma unroll
    for (int n = 0; n < 8; ++n) {
        int col = n * 16 + colbase;
        float bz = bias[col];
#pragma unroll
        for (int rb = 0; rb < 2; ++rb)
#pragma unroll
            for (int rr = 0; rr < 4; ++rr) {
                long r = wbase + rb * 16 + orow + rr;
                if (r < T) out[r * 128 + col] = (__bf16)(acc[n][rb][rr] + bz);
            }
    }

    // fused elementwise: addout[r] = src0[r] + src1[r] for this block's 128 rows
    const long eb = (long)blockIdx.x * 128 * 128;
#pragma unroll
    for (int j = 0; j < 16; ++j) {
        int vec = j * 256 + threadIdx.x;                 // 0..4095
        long r = (long)blockIdx.x * 128 + (vec >> 5);
        if (r < T) {
            long off = eb + (long)vec * 4;
            f32x4 x = *(const f32x4*)(src0 + off);
            f32x4 y = *(const f32x4*)(src1 + off);
            f32x4 o;
            o[0] = x[0] + y[0]; o[1] = x[1] + y[1];
            o[2] = x[2] + y[2]; o[3] = x[3] + y[3];
            *(f32x4*)(addout + off) = o;
        }
    }
}

// ================= edge GEMM (16 rows/wave: 32-AGPR acc, ~96 free arch VGPRs) =====
// out[e] = relu(G[idx[e]] + A[e]@W), A = [arow (bf16 rows, t<4) | efrag (t>=4)].
// PHASE 1: arow = prev_bf -> m1 (bf16).  PHASE 2: arow = m1 -> out_m (f32).
// Barrier-free; per-wave-private LDS for epilogue transpose only. A prefetched 1 t ahead.
template <int PHASE>
__global__ __launch_bounds__(256, 4) void edge_gemm(
    const __bf16* __restrict__ arow, const __bf16* __restrict__ efrag,
    const __bf16* __restrict__ WT, const __bf16* __restrict__ G,
    const int* __restrict__ idx, __bf16* __restrict__ outb,
    float* __restrict__ outf, int E) {
    __shared__ char lds[4][8192];
    const int wave = threadIdx.x >> 6;
    const int lane = threadIdx.x & 63;
    const int l16 = lane & 15;
    const int kch = lane >> 4;
    const long wrow = (long)blockIdx.x * 64 + wave * 16;   // 16 rows per wave
    const long maxtile = (long)(E - 1) >> 4;

    long rA = wrow + l16; if (rA >= E) rA = E - 1;          // A row for t<4
    long tile = wrow >> 4; if (tile > maxtile) tile = maxtile;

    auto loadA = [&](int t) -> bf16x8 {
        if (t < 4) return *(const bf16x8*)(arow + rA * 128 + t * 32 + kch * 8);
        return *(const bf16x8*)(efrag + (tile * 4 + (t - 4)) * 512 + lane * 8);
    };

    f32x4 acc[8];
#pragma unroll
    for (int n = 0; n < 8; ++n) acc[n] = (f32x4){0.f, 0.f, 0.f, 0.f};

    bf16x8 a_cur = loadA(0);
#pragma unroll
    for (int t = 0; t < 8; ++t) {
        bf16x8 a_nxt;
        if (t < 7) a_nxt = loadA(t + 1);
        const __bf16* bbase = WT + (long)t * 4096 + lane * 8;
#pragma unroll
        for (int n = 0; n < 8; ++n) {
            bf16x8 b = *(const bf16x8*)(bbase + n * 512);
            acc[n] = __builtin_amdgcn_mfma_f32_16x16x32_bf16(a_cur, b, acc[n], 0, 0, 0);
        }
        a_cur = a_nxt;
    }

    // epilogue: per-wave LDS transpose -> coalesced G-add + full-line stores
    float* lbuf = (float*)&lds[wave][0];   // [16][128] f32, slot-swizzled
    const int slotcol = lane & 31;
    const int rhalf = lane >> 5;
#pragma unroll
    for (int n = 0; n < 8; ++n)
#pragma unroll
        for (int rr = 0; rr < 4; ++rr) {
            int row = kch * 4 + rr;
            int col = n * 16 + l16;
            int slot = col >> 2;
            lbuf[row * 128 + (((slot ^ (row & 7)) << 2) | (col & 3))] = acc[n][rr];
        }
#pragma unroll
    for (int j = 0; j < 8; ++j) {
        int row = 2 * j + rhalf;
        long eo = wrow + row;
        f32x4 v = *(const f32x4*)&lbuf[row * 128 + ((slotcol ^ (row & 7)) << 2)];
        if (eo < E) {
            int g = idx[eo];
            bf16x4 gb = *(const bf16x4*)(G + (long)g * 128 + slotcol * 4);
            f32x4 o;
#pragma unroll
            for (int i = 0; i < 4; ++i) {
                float x = v[i] + (float)gb[i];
                o[i] = x > 0.f ? x : 0.f;
            }
            if (PHASE == 1) {
                bf16x4 ob;
#pragma unroll
                for (int i = 0; i < 4; ++i) ob[i] = (__bf16)o[i];
                *(bf16x4*)(outb + eo * 128 + slotcol * 4) = ob;
            } else {
                *(f32x4*)(outf + eo * 128 + slotcol * 4) = o;
            }
        }
    }
}

extern "C" void kernel_launch(void* const* d_in, const int* in_sizes, int n_in,
                              void* d_out, int out_size, void* d_ws, size_t ws_size,
                              hipStream_t stream) {
    const float* prev_m   = (const float*)d_in[0];
    const float* variable = (const float*)d_in[1];
    const float* factor   = (const float*)d_in[2];
    const float* eattr    = (const float*)d_in[3];
    const int*   v_to_f   = (const int*)d_in[4];
    const int*   f_to_v   = (const int*)d_in[5];
    const float* Wv       = (const float*)d_in[6];
    const float* bv       = (const float*)d_in[7];
    const float* Wf       = (const float*)d_in[8];
    const float* bf       = (const float*)d_in[9];

    const int E = in_sizes[0] / 128;
    const int V = in_sizes[1] / 128;
    const int F = in_sizes[2] / 128;
    const int NT = V + F;
    const int eblocks64 = (E + 63) / 64;
    const int ntiles = (E + 15) / 16;
    const int nunits = ntiles * 4;

    float* out_m        = (float*)d_out;               // [E,128]
    float* out_factor   = out_m + (long)E * 128;       // [F,128]
    float* out_variable = out_factor + (long)F * 128;  // [V,128]

    char* ws = (char*)d_ws;
    float* sum_f_to_v = (float*)ws;  ws += (long)V * 128 * 4;
    float* sum_v_to_f = (float*)ws;  ws += (long)F * 128 * 4;
    __bf16* m1        = (__bf16*)ws; ws += (long)E * 128 * 2;
    __bf16* prev_bf   = (__bf16*)ws; ws += (long)E * 128 * 2;
    __bf16* efrag     = (__bf16*)ws; ws += (long)nunits * 512 * 2;
    __bf16* G1        = (__bf16*)ws; ws += (long)V * 128 * 2;
    __bf16* G2        = (__bf16*)ws; ws += (long)F * 128 * 2;
    __bf16* Wtab_v    = (__bf16*)ws; ws += 256 * 128 * 2;
    __bf16* Wedge_v   = (__bf16*)ws; ws += 256 * 128 * 2;
    __bf16* Wtab_f    = (__bf16*)ws; ws += 256 * 128 * 2;
    __bf16* Wedge_f   = (__bf16*)ws; ws += 256 * 128 * 2;
    int* counts       = (int*)ws;    ws += (long)NT * 4;
    int* offsets      = (int*)ws;    ws += (long)(NT + 1) * 4;
    int* cursors      = (int*)ws;    ws += (long)NT * 4;
    int* bucket       = (int*)ws;    ws += (long)2 * E * 4;
    int* partials     = (int*)ws;    ws += 256 * 4;

    hipMemsetAsync(counts, 0, (size_t)NT * 4, stream);

    pack_all<<<dim3(512), dim3(256), 0, stream>>>(Wv, Wf, Wtab_v, Wedge_v, Wtab_f, Wedge_f);

    // ---- eattr -> fragment order (used by BOTH edge GEMMs) ----
    conv_eattr<<<dim3((nunits + 3) / 4), dim3(256), 0, stream>>>(eattr, efrag, E, nunits);

    // ---- CSR build ----
    hist_kernel<<<dim3(2048), dim3(256), 0, stream>>>(v_to_f, f_to_v, counts, V, E);
    int nb = (NT + SCAN_BLOCK * SCAN_ELEMS - 1) / (SCAN_BLOCK * SCAN_ELEMS);  // 147
    scan_pass1<<<dim3(nb), dim3(SCAN_BLOCK), 0, stream>>>(counts, partials, NT);
    scan_pass3<<<dim3(nb), dim3(SCAN_BLOCK), 0, stream>>>(counts, partials, offsets, cursors,
                                                          NT, 2 * E);
    fill_kernel<<<dim3(2048), dim3(256), 0, stream>>>(v_to_f, f_to_v, cursors, bucket, V, E);

    // ---- sum_f_to_v = segsum(prev_m); also emit prev_bf (bf16 rows) ----
    gsum_f32<<<dim3((V + 3) / 4), dim3(256), 0, stream>>>(
        prev_m, bucket, offsets, 0, sum_f_to_v, prev_bf, V);

    // ---- G1[v] = var@Wv1 + sum@Wv2 + bv ; new_variable = var + sum ----
    table_gemm<<<dim3((V + 127) / 128), dim3(256), 0, stream>>>(
        variable, sum_f_to_v, Wtab_v, bv, G1, out_variable, V);

    // ---- m1 = relu(G1[v[e]] - prev@Wv2 + eattr@Wv3) ----
    edge_gemm<1><<<dim3(eblocks64), dim3(256), 0, stream>>>(
        prev_bf, efrag, Wedge_v, G1, v_to_f, m1, nullptr, E);

    // ---- sum_v_to_f = segsum(m1) ----
    gsum_bf16<<<dim3((F + 3) / 4), dim3(256), 0, stream>>>(
        m1, bucket, offsets, V, sum_v_to_f, F);

    // ---- G2[f] = factor@Wf1 + sum@Wf2 + bf ; new_factor = factor + sum ----
    table_gemm<<<dim3((F + 127) / 128), dim3(256), 0, stream>>>(
        factor, sum_v_to_f, Wtab_f, bf, G2, out_factor, F);

    // ---- out_m = relu(G2[f[e]] - m1@Wf2 + eattr@Wf3) ----
    edge_gemm<2><<<dim3(eblocks64), dim3(256), 0, stream>>>(
        m1, efrag, Wedge_f, G2, f_to_v, nullptr, out_m, E);
}

// Round 15
// 726.997 us; speedup vs baseline: 1.0979x; 1.0979x over previous
//
#include <hip/hip_runtime.h>

typedef __attribute__((ext_vector_type(8))) __bf16 bf16x8;
typedef __attribute__((ext_vector_type(4))) __bf16 bf16x4;
typedef __attribute__((ext_vector_type(2))) __bf16 bf16x2;
typedef __attribute__((ext_vector_type(4))) float f32x4;

__device__ inline bf16x8 pack8(f32x4 u0, f32x4 u1) {
    bf16x8 r;
    r[0] = (__bf16)u0[0]; r[1] = (__bf16)u0[1]; r[2] = (__bf16)u0[2]; r[3] = (__bf16)u0[3];
    r[4] = (__bf16)u1[0]; r[5] = (__bf16)u1[1]; r[6] = (__bf16)u1[2]; r[7] = (__bf16)u1[3];
    return r;
}

// ---- pack all 4 weight blocks into MFMA B-fragment order (one launch) ----
__global__ void pack_all(const float* __restrict__ Wv, const float* __restrict__ Wf,
                         __bf16* __restrict__ Wtab_v, __bf16* __restrict__ Wedge_v,
                         __bf16* __restrict__ Wtab_f, __bf16* __restrict__ Wedge_f) {
    int which = blockIdx.x >> 7;                       // 0..3
    int i = ((blockIdx.x & 127) << 8) + threadIdx.x;   // 0..32767
    const float* W = (which < 2) ? Wv : Wf;
    __bf16* out = (which == 0) ? Wtab_v : (which == 1) ? Wedge_v
                 : (which == 2) ? Wtab_f : Wedge_f;
    int baseA = (which & 1) ? 128 : 0;
    float sA  = (which & 1) ? -1.f : 1.f;
    int baseB = (which & 1) ? 256 : 128;
    int k = i >> 7, d = i & 127;
    float v = (k < 128) ? sA * W[(long)(baseA + k) * 128 + d]
                        : W[(long)(baseB + (k - 128)) * 128 + d];
    int t = k >> 5, n = d >> 4;
    int lane = (d & 15) | (((k >> 3) & 3) << 4);
    int j = k & 7;
    out[((long)(t * 8 + n) * 64 + lane) * 8 + j] = (__bf16)v;
}

// ================= CSR build (counts -> scan -> fill) =================

__global__ void hist_kernel(const int* __restrict__ v_to_f, const int* __restrict__ f_to_v,
                            int* __restrict__ counts, int V, int E) {
    int stride = gridDim.x * blockDim.x;
    for (int e = blockIdx.x * blockDim.x + threadIdx.x; e < E; e += stride) {
        atomicAdd(&counts[v_to_f[e]], 1);
        atomicAdd(&counts[V + f_to_v[e]], 1);
    }
}

#define SCAN_BLOCK 256
#define SCAN_ELEMS 4   // 1024 elements per block

__global__ void scan_pass1(const int* __restrict__ counts, int* __restrict__ partials, int N) {
    int t = threadIdx.x;
    int base = blockIdx.x * (SCAN_BLOCK * SCAN_ELEMS) + t * SCAN_ELEMS;
    int s = 0;
#pragma unroll
    for (int j = 0; j < SCAN_ELEMS; ++j) {
        int i = base + j;
        if (i < N) s += counts[i];
    }
#pragma unroll
    for (int off = 1; off < 64; off <<= 1) s += __shfl_xor(s, off);
    __shared__ int lds[4];
    if ((t & 63) == 0) lds[t >> 6] = s;
    __syncthreads();
    if (t == 0) partials[blockIdx.x] = lds[0] + lds[1] + lds[2] + lds[3];
}

__global__ void scan_pass3(const int* __restrict__ counts, const int* __restrict__ partials,
                           int* __restrict__ offsets, int* __restrict__ cursors,
                           int N, int total) {
    int t = threadIdx.x;
    int pre = 0;
    for (int i = 0; i < (int)blockIdx.x; ++i) pre += partials[i];
    int base = blockIdx.x * (SCAN_BLOCK * SCAN_ELEMS) + t * SCAN_ELEMS;
    int c[SCAN_ELEMS];
    int s = 0;
#pragma unroll
    for (int j = 0; j < SCAN_ELEMS; ++j) {
        int i = base + j;
        c[j] = (i < N) ? counts[i] : 0;
        s += c[j];
    }
    int lane = t & 63, w = t >> 6;
    int x = s;
#pragma unroll
    for (int off = 1; off < 64; off <<= 1) { int y = __shfl_up(x, off); if (lane >= off) x += y; }
    __shared__ int lds[4];
    if (lane == 63) lds[w] = x;
    __syncthreads();
    int add = 0;
    for (int i = 0; i < w; ++i) add += lds[i];
    int run = x + add - s + pre;
#pragma unroll
    for (int j = 0; j < SCAN_ELEMS; ++j) {
        int i = base + j;
        if (i < N) { offsets[i] = run; cursors[i] = run; }
        run += c[j];
    }
    if (blockIdx.x == 0 && t == 0) offsets[N] = total;
}

__global__ void fill_kernel(const int* __restrict__ v_to_f, const int* __restrict__ f_to_v,
                            int* __restrict__ cursors, int* __restrict__ bucket, int V, int E) {
    int stride = gridDim.x * blockDim.x;
    for (int e = blockIdx.x * blockDim.x + threadIdx.x; e < E; e += stride) {
        int p = atomicAdd(&cursors[v_to_f[e]], 1);
        bucket[p] = e;
        int q = atomicAdd(&cursors[V + f_to_v[e]], 1);
        bucket[q] = e;
    }
}

// ================= gather-sum (segment sum, no atomics, unroll-4) =================

__global__ __launch_bounds__(256) void gsum_f32(
    const float* __restrict__ src, const int* __restrict__ bucket,
    const int* __restrict__ offsets, int toff,
    float* __restrict__ sumout, int T) {
    int gw = (int)((blockIdx.x * (long)blockDim.x + threadIdx.x) >> 6);
    if (gw >= T) return;
    int lane = threadIdx.x & 63;
    int start = offsets[toff + gw], end = offsets[toff + gw + 1];
    float ax = 0.f, ay = 0.f, bx = 0.f, by = 0.f;
    float cx = 0.f, cy = 0.f, dx = 0.f, dy = 0.f;
    int i = start;
    for (; i + 3 < end; i += 4) {
        int e0 = bucket[i], e1 = bucket[i + 1], e2 = bucket[i + 2], e3 = bucket[i + 3];
        float2 v0 = *(const float2*)(src + (long)e0 * 128 + lane * 2);
        float2 v1 = *(const float2*)(src + (long)e1 * 128 + lane * 2);
        float2 v2 = *(const float2*)(src + (long)e2 * 128 + lane * 2);
        float2 v3 = *(const float2*)(src + (long)e3 * 128 + lane * 2);
        ax += v0.x; ay += v0.y; bx += v1.x; by += v1.y;
        cx += v2.x; cy += v2.y; dx += v3.x; dy += v3.y;
    }
    for (; i < end; ++i) {
        int e0 = bucket[i];
        float2 v0 = *(const float2*)(src + (long)e0 * 128 + lane * 2);
        ax += v0.x; ay += v0.y;
    }
    ax += bx + cx + dx; ay += by + cy + dy;
    long o = (long)gw * 128 + lane * 2;
    *(float2*)(sumout + o) = make_float2(ax, ay);
}

__global__ __launch_bounds__(256) void gsum_bf16(
    const __bf16* __restrict__ src, const int* __restrict__ bucket,
    const int* __restrict__ offsets, int toff,
    float* __restrict__ sumout, int T) {
    int gw = (int)((blockIdx.x * (long)blockDim.x + threadIdx.x) >> 6);
    if (gw >= T) return;
    int lane = threadIdx.x & 63;
    int start = offsets[toff + gw], end = offsets[toff + gw + 1];
    float ax = 0.f, ay = 0.f, bx = 0.f, by = 0.f;
    float cx = 0.f, cy = 0.f, dx = 0.f, dy = 0.f;
    int i = start;
    for (; i + 3 < end; i += 4) {
        int e0 = bucket[i], e1 = bucket[i + 1], e2 = bucket[i + 2], e3 = bucket[i + 3];
        bf16x2 v0 = *(const bf16x2*)(src + (long)e0 * 128 + lane * 2);
        bf16x2 v1 = *(const bf16x2*)(src + (long)e1 * 128 + lane * 2);
        bf16x2 v2 = *(const bf16x2*)(src + (long)e2 * 128 + lane * 2);
        bf16x2 v3 = *(const bf16x2*)(src + (long)e3 * 128 + lane * 2);
        ax += (float)v0[0]; ay += (float)v0[1]; bx += (float)v1[0]; by += (float)v1[1];
        cx += (float)v2[0]; cy += (float)v2[1]; dx += (float)v3[0]; dy += (float)v3[1];
    }
    for (; i < end; ++i) {
        int e0 = bucket[i];
        bf16x2 v0 = *(const bf16x2*)(src + (long)e0 * 128 + lane * 2);
        ax += (float)v0[0]; ay += (float)v0[1];
    }
    ax += bx + cx + dx; ay += by + cy + dy;
    long o = (long)gw * 128 + lane * 2;
    *(float2*)(sumout + o) = make_float2(ax, ay);
}

// ====== table GEMM: G[r] = src0[r]@WA + src1[r]@WB + bias; addout = src0+src1 ======
__global__ __launch_bounds__(256, 4) void table_gemm(
    const float* __restrict__ src0, const float* __restrict__ src1,
    const __bf16* __restrict__ WT, const float* __restrict__ bias,
    __bf16* __restrict__ out, float* __restrict__ addout, int T) {
    const int wave = threadIdx.x >> 6;
    const int lane = threadIdx.x & 63;
    const int row = lane & 15;
    const int kch = lane >> 4;
    const long wbase = ((long)blockIdx.x * 4 + wave) * 32;

    const float* p0[2]; const float* p1[2];
#pragma unroll
    for (int rb = 0; rb < 2; ++rb) {
        long r = wbase + rb * 16 + row;
        long rl = (r < T) ? r : (T - 1);
        p0[rb] = src0 + rl * 128 + kch * 8;
        p1[rb] = src1 + rl * 128 + kch * 8;
    }

    f32x4 acc[8][2];
#pragma unroll
    for (int n = 0; n < 8; ++n) {
        acc[n][0] = (f32x4){0.f, 0.f, 0.f, 0.f};
        acc[n][1] = (f32x4){0.f, 0.f, 0.f, 0.f};
    }

#pragma unroll
    for (int t = 0; t < 8; ++t) {
        bf16x8 a[2];
#pragma unroll
        for (int rb = 0; rb < 2; ++rb) {
            const float* p = (t < 4) ? (p0[rb] + t * 32) : (p1[rb] + (t - 4) * 32);
            f32x4 u0 = *(const f32x4*)p;
            f32x4 u1 = *(const f32x4*)(p + 4);
            a[rb] = pack8(u0, u1);
        }
        const __bf16* bbase = WT + (long)t * 8 * 512 + lane * 8;
#pragma unroll
        for (int n = 0; n < 8; ++n) {
            bf16x8 b = *(const bf16x8*)(bbase + n * 512);
            acc[n][0] = __builtin_amdgcn_mfma_f32_16x16x32_bf16(a[0], b, acc[n][0], 0, 0, 0);
            acc[n][1] = __builtin_amdgcn_mfma_f32_16x16x32_bf16(a[1], b, acc[n][1], 0, 0, 0);
        }
    }

    const int colbase = lane & 15;
    const int orow = (lane >> 4) * 4;
#pragma unroll
    for (int n = 0; n < 8; ++n) {
        int col = n * 16 + colbase;
        float bz = bias[col];
#pragma unroll
        for (int rb = 0; rb < 2; ++rb)
#pragma unroll
            for (int rr = 0; rr < 4; ++rr) {
                long r = wbase + rb * 16 + orow + rr;
                if (r < T) out[r * 128 + col] = (__bf16)(acc[n][rb][rr] + bz);
            }
    }

    // fused elementwise: addout[r] = src0[r] + src1[r] for this block's 128 rows
    const long eb = (long)blockIdx.x * 128 * 128;
#pragma unroll
    for (int j = 0; j < 16; ++j) {
        int vec = j * 256 + threadIdx.x;                 // 0..4095
        long r = (long)blockIdx.x * 128 + (vec >> 5);
        if (r < T) {
            long off = eb + (long)vec * 4;
            f32x4 x = *(const f32x4*)(src0 + off);
            f32x4 y = *(const f32x4*)(src1 + off);
            f32x4 o;
            o[0] = x[0] + y[0]; o[1] = x[1] + y[1];
            o[2] = x[2] + y[2]; o[3] = x[3] + y[3];
            *(f32x4*)(addout + off) = o;
        }
    }
}

// ================= edge GEMM (16 rows/wave, LB(256,6): 6 waves/SIMD) =================
// out[e] = relu(G[idx[e]] + A[e]@W), A = [arow rows (t<4) | eattr rows (t>=4)].
// PHASE 1: arow = prev_m (f32) -> m1 (bf16).  PHASE 2: arow = m1 (bf16) -> out_m (f32).
// Barrier-free; per-wave-private LDS epilogue transpose. A prefetched 1 t ahead.
template <int PHASE>
__global__ __launch_bounds__(256, 6) void edge_gemm(
    const float* __restrict__ arowf, const __bf16* __restrict__ arowb,
    const float* __restrict__ eattr, const __bf16* __restrict__ WT,
    const __bf16* __restrict__ G, const int* __restrict__ idx,
    __bf16* __restrict__ outb, float* __restrict__ outf, int E) {
    __shared__ char lds[4][8192];
    const int wave = threadIdx.x >> 6;
    const int lane = threadIdx.x & 63;
    const int l16 = lane & 15;
    const int kch = lane >> 4;
    const long wrow = (long)blockIdx.x * 64 + wave * 16;   // 16 rows per wave
    long rA = wrow + l16; if (rA >= E) rA = E - 1;

    auto loadA = [&](int t) -> bf16x8 {
        if (t < 4) {
            if (PHASE == 1) {
                const float* p = arowf + rA * 128 + t * 32 + kch * 8;
                f32x4 u0 = *(const f32x4*)p;
                f32x4 u1 = *(const f32x4*)(p + 4);
                return pack8(u0, u1);
            } else {
                return *(const bf16x8*)(arowb + rA * 128 + t * 32 + kch * 8);
            }
        }
        const float* p = eattr + rA * 128 + (t - 4) * 32 + kch * 8;
        f32x4 u0 = *(const f32x4*)p;
        f32x4 u1 = *(const f32x4*)(p + 4);
        return pack8(u0, u1);
    };

    f32x4 acc[8];
#pragma unroll
    for (int n = 0; n < 8; ++n) acc[n] = (f32x4){0.f, 0.f, 0.f, 0.f};

    bf16x8 a_cur = loadA(0);
#pragma unroll
    for (int t = 0; t < 8; ++t) {
        bf16x8 a_nxt;
        if (t < 7) a_nxt = loadA(t + 1);
        const __bf16* bbase = WT + (long)t * 4096 + lane * 8;
#pragma unroll
        for (int n = 0; n < 8; ++n) {
            bf16x8 b = *(const bf16x8*)(bbase + n * 512);
            acc[n] = __builtin_amdgcn_mfma_f32_16x16x32_bf16(a_cur, b, acc[n], 0, 0, 0);
        }
        a_cur = a_nxt;
    }

    // epilogue: per-wave LDS transpose -> coalesced G-add + full-line stores
    float* lbuf = (float*)&lds[wave][0];   // [16][128] f32, slot-swizzled
    const int slotcol = lane & 31;
    const int rhalf = lane >> 5;
#pragma unroll
    for (int n = 0; n < 8; ++n)
#pragma unroll
        for (int rr = 0; rr < 4; ++rr) {
            int row = kch * 4 + rr;
            int col = n * 16 + l16;
            int slot = col >> 2;
            lbuf[row * 128 + (((slot ^ (row & 7)) << 2) | (col & 3))] = acc[n][rr];
        }
#pragma unroll
    for (int j = 0; j < 8; ++j) {
        int row = 2 * j + rhalf;
        long eo = wrow + row;
        f32x4 v = *(const f32x4*)&lbuf[row * 128 + ((slotcol ^ (row & 7)) << 2)];
        if (eo < E) {
            int g = idx[eo];
            bf16x4 gb = *(const bf16x4*)(G + (long)g * 128 + slotcol * 4);
            f32x4 o;
#pragma unroll
            for (int i = 0; i < 4; ++i) {
                float x = v[i] + (float)gb[i];
                o[i] = x > 0.f ? x : 0.f;
            }
            if (PHASE == 1) {
                bf16x4 ob;
#pragma unroll
                for (int i = 0; i < 4; ++i) ob[i] = (__bf16)o[i];
                *(bf16x4*)(outb + eo * 128 + slotcol * 4) = ob;
            } else {
                *(f32x4*)(outf + eo * 128 + slotcol * 4) = o;
            }
        }
    }
}

extern "C" void kernel_launch(void* const* d_in, const int* in_sizes, int n_in,
                              void* d_out, int out_size, void* d_ws, size_t ws_size,
                              hipStream_t stream) {
    const float* prev_m   = (const float*)d_in[0];
    const float* variable = (const float*)d_in[1];
    const float* factor   = (const float*)d_in[2];
    const float* eattr    = (const float*)d_in[3];
    const int*   v_to_f   = (const int*)d_in[4];
    const int*   f_to_v   = (const int*)d_in[5];
    const float* Wv       = (const float*)d_in[6];
    const float* bv       = (const float*)d_in[7];
    const float* Wf       = (const float*)d_in[8];
    const float* bf       = (const float*)d_in[9];

    const int E = in_sizes[0] / 128;
    const int V = in_sizes[1] / 128;
    const int F = in_sizes[2] / 128;
    const int NT = V + F;
    const int eblocks64 = (E + 63) / 64;

    float* out_m        = (float*)d_out;               // [E,128]
    float* out_factor   = out_m + (long)E * 128;       // [F,128]
    float* out_variable = out_factor + (long)F * 128;  // [V,128]

    char* ws = (char*)d_ws;
    float* sum_f_to_v = (float*)ws;  ws += (long)V * 128 * 4;
    float* sum_v_to_f = (float*)ws;  ws += (long)F * 128 * 4;
    __bf16* m1        = (__bf16*)ws; ws += (long)E * 128 * 2;
    __bf16* G1        = (__bf16*)ws; ws += (long)V * 128 * 2;
    __bf16* G2        = (__bf16*)ws; ws += (long)F * 128 * 2;
    __bf16* Wtab_v    = (__bf16*)ws; ws += 256 * 128 * 2;
    __bf16* Wedge_v   = (__bf16*)ws; ws += 256 * 128 * 2;
    __bf16* Wtab_f    = (__bf16*)ws; ws += 256 * 128 * 2;
    __bf16* Wedge_f   = (__bf16*)ws; ws += 256 * 128 * 2;
    int* counts       = (int*)ws;    ws += (long)NT * 4;
    int* offsets      = (int*)ws;    ws += (long)(NT + 1) * 4;
    int* cursors      = (int*)ws;    ws += (long)NT * 4;
    int* bucket       = (int*)ws;    ws += (long)2 * E * 4;
    int* partials     = (int*)ws;    ws += 256 * 4;

    hipMemsetAsync(counts, 0, (size_t)NT * 4, stream);

    pack_all<<<dim3(512), dim3(256), 0, stream>>>(Wv, Wf, Wtab_v, Wedge_v, Wtab_f, Wedge_f);

    // ---- CSR build ----
    hist_kernel<<<dim3(2048), dim3(256), 0, stream>>>(v_to_f, f_to_v, counts, V, E);
    int nb = (NT + SCAN_BLOCK * SCAN_ELEMS - 1) / (SCAN_BLOCK * SCAN_ELEMS);  // 147
    scan_pass1<<<dim3(nb), dim3(SCAN_BLOCK), 0, stream>>>(counts, partials, NT);
    scan_pass3<<<dim3(nb), dim3(SCAN_BLOCK), 0, stream>>>(counts, partials, offsets, cursors,
                                                          NT, 2 * E);
    fill_kernel<<<dim3(2048), dim3(256), 0, stream>>>(v_to_f, f_to_v, cursors, bucket, V, E);

    // ---- sum_f_to_v = segsum(prev_m) ----
    gsum_f32<<<dim3((V + 3) / 4), dim3(256), 0, stream>>>(
        prev_m, bucket, offsets, 0, sum_f_to_v, V);

    // ---- G1[v] = var@Wv1 + sum@Wv2 + bv ; new_variable = var + sum ----
    table_gemm<<<dim3((V + 127) / 128), dim3(256), 0, stream>>>(
        variable, sum_f_to_v, Wtab_v, bv, G1, out_variable, V);

    // ---- m1 = relu(G1[v[e]] - prev@Wv2 + eattr@Wv3) ----
    edge_gemm<1><<<dim3(eblocks64), dim3(256), 0, stream>>>(
        prev_m, nullptr, eattr, Wedge_v, G1, v_to_f, m1, nullptr, E);

    // ---- sum_v_to_f = segsum(m1) ----
    gsum_bf16<<<dim3((F + 3) / 4), dim3(256), 0, stream>>>(
        m1, bucket, offsets, V, sum_v_to_f, F);

    // ---- G2[f] = factor@Wf1 + sum@Wf2 + bf ; new_factor = factor + sum ----
    table_gemm<<<dim3((F + 127) / 128), dim3(256), 0, stream>>>(
        factor, sum_v_to_f, Wtab_f, bf, G2, out_factor, F);

    // ---- out_m = relu(G2[f[e]] - m1@Wf2 + eattr@Wf3) ----
    edge_gemm<2><<<dim3(eblocks64), dim3(256), 0, stream>>>(
        nullptr, m1, eattr, Wedge_f, G2, f_to_v, nullptr, out_m, E);
}